// Round 4
// baseline (275.235 us; speedup 1.0000x reference)
//
#include <hip/hip_runtime.h>
#include <stdint.h>

#define K_DIM 1024
#define N_DIM 1024
#define M_DIM 65536

typedef __bf16 bf16_t;
typedef __bf16 bf16x8 __attribute__((ext_vector_type(8)));
typedef float f32x4 __attribute__((ext_vector_type(4)));

#define GLOAD_LDS16(g, l) __builtin_amdgcn_global_load_lds( \
    (const __attribute__((address_space(1))) void*)(g),     \
    (__attribute__((address_space(3))) void*)(l), 16, 0, 0)

#define VMCNT(n) asm volatile("s_waitcnt vmcnt(%0)" ::"n"(n) : "memory")
#define LGKM(n) asm volatile("s_waitcnt lgkmcnt(%0)" ::"n"(n) : "memory")
#define SCHEDB() __builtin_amdgcn_sched_barrier(0)

// ---------------------------------------------------------------------------
// Quantize-dequantize to bf16 (semantics unchanged; now one launch handles
// both w and x: blocks [0,512) do w (1 item/thread), the rest grid-stride x).
// ---------------------------------------------------------------------------
__global__ __launch_bounds__(256) void quant_dequant_kernel(
    const float* __restrict__ x, bf16_t* __restrict__ xd, long long nx,
    const float* __restrict__ w, bf16_t* __restrict__ wd, long long nw) {
  const float* in;
  bf16_t* out;
  long long i, stride, n;
  if (blockIdx.x < 512) {
    in = w; out = wd; n = nw;
    i = (long long)blockIdx.x * blockDim.x + threadIdx.x;
    stride = 512ll * blockDim.x;
  } else {
    in = x; out = xd; n = nx;
    i = (long long)(blockIdx.x - 512) * blockDim.x + threadIdx.x;
    stride = (long long)(gridDim.x - 512) * blockDim.x;
  }
  for (; i < n; i += stride) {
    long long base = i * 8;
    f32x4 v0 = *reinterpret_cast<const f32x4*>(in + base);
    f32x4 v1 = *reinterpret_cast<const f32x4*>(in + base + 4);
    float mx = 0.0f;
#pragma unroll
    for (int j = 0; j < 4; ++j) {
      mx = fmaxf(mx, fabsf(v0[j]));
      mx = fmaxf(mx, fabsf(v1[j]));
    }
    mx = fmaxf(mx, __shfl_xor(mx, 1));
    mx = fmaxf(mx, __shfl_xor(mx, 2));
    float s = fmaxf(mx / 7.5f, 1e-30f);
    bf16x8 o;
#pragma unroll
    for (int j = 0; j < 8; ++j) {
      float xv = (j < 4) ? v0[j] : v1[j - 4];
      float y = xv / s;  // fp32 div, like reference
      float m = fabsf(y);
      float h, hinv;
      if (m < 2.0f)      { h = 0.125f; hinv = 8.0f; }
      else if (m < 4.0f) { h = 0.25f;  hinv = 4.0f; }
      else               { h = 0.5f;   hinv = 2.0f; }
      float nn = m * hinv;  // exact (power-of-2 scale)
      float kf = floorf(nn);
      float fr = nn - kf;   // exact
      float up = (fr > 0.5f || (fr == 0.5f && y < 0.0f)) ? 1.0f : 0.0f;
      float q = fminf((kf + up) * h, 7.5f);
      o[j] = (bf16_t)(copysignf(q, y) * s);
    }
    *reinterpret_cast<bf16x8*>(out + base) = o;
  }
}

// ---------------------------------------------------------------------------
// bf16 GEMM C = A*B^T + bias. 256x256 tile, BK=32, 8 waves (2M x 4N),
// 4-stage LDS ring (4 x 32KB), stage 3 K-tiles ahead.
// Round-4 change: m201-style per-phase schedule. Each K-tile = 2 phases
// (m-half split); each phase:
//   {ds_reads (8 or 4 b128) | 2 global_load_lds | vmcnt(8) | s_barrier |
//    lgkm(0) | sched_barrier | setprio(1) 16 MFMA setprio(0) | s_barrier}
// vmcnt(8) at every phase retires exactly 2 loads/phase (steady state), so
// buf[t] is fully landed at PB(t-1)'s barrier1 — one barrier before PA(t)'s
// reads. lgkm(0) precedes every wave's MFMA, so at barrier2 all reads of the
// current buffer are retired before any wave stages over buf[t-1]. The load
// queue never drains below 8 until the tail (vmcnt 4 -> 0).
// Swizzle (verified 0 conflicts in r3): 16B slot' = slot ^ ((row>>1)&3);
// staging source col pre-swizzled: col8 = (tid&3)^((tid>>3)&3), row = tid>>2.
// ---------------------------------------------------------------------------
__global__ __launch_bounds__(512, 2) void mx_gemm(
    const bf16_t* __restrict__ A, const bf16_t* __restrict__ B,
    const float* __restrict__ bias, float* __restrict__ C) {
  __shared__ char lds[131072];

  const int tid = threadIdx.x;
  const int lane = tid & 63;
  const int wid = tid >> 6;
  const int wm = wid >> 2;  // 0..1  (128-row half)
  const int wn = wid & 3;   // 0..3  (64-col slice)

  // XCD-grouped mapping (verified: A fetched ~once from HBM).
  const int b = blockIdx.x;
  const int xcd = b & 7;
  const int t = b >> 3;
  const int m_tile = xcd * 32 + (t >> 2);  // [0,256)
  const int n_tile = t & 3;                // [0,4)

  const int R0 = tid >> 2;
  const int c0 = ((tid & 3) ^ ((tid >> 3) & 3)) * 8;  // elems
  const bf16_t* aS0 = A + (size_t)(m_tile * 256 + R0) * K_DIM + c0;
  const bf16_t* aS1 = aS0 + (size_t)128 * K_DIM;
  const bf16_t* bS0 = B + (size_t)(n_tile * 256 + R0) * K_DIM + c0;
  const bf16_t* bS1 = bS0 + (size_t)128 * K_DIM;
  const int dstOff = tid * 16;

#define STAGE_A(u)                                  \
  {                                                 \
    char* sd_ = lds + ((u) & 3) * 32768;            \
    const int ko_ = (u) * 32;                       \
    GLOAD_LDS16(aS0 + ko_, sd_ + dstOff);           \
    GLOAD_LDS16(aS1 + ko_, sd_ + 8192 + dstOff);    \
  }
#define STAGE_B(u)                                  \
  {                                                 \
    char* sd_ = lds + ((u) & 3) * 32768;            \
    const int ko_ = (u) * 32;                       \
    GLOAD_LDS16(bS0 + ko_, sd_ + 16384 + dstOff);   \
    GLOAD_LDS16(bS1 + ko_, sd_ + 24576 + dstOff);   \
  }

  // Fragment reads (r3 zero-conflict family): phys slot = (lane>>4) ^
  // ((row>>1)&3), row = lane&15 within a 16-row frag.
  const int ps = (((lane >> 4) ^ ((lane >> 1) & 3)) << 4);
  const int rowb = (lane & 15) * 64 + ps;
  const int aOff = wm * 8192 + rowb;          // + half*4096 + i*1024
  const int bOff = 16384 + wn * 4096 + rowb;  // + j*1024

  f32x4 acc[8][4];
#pragma unroll
  for (int i = 0; i < 8; ++i)
#pragma unroll
    for (int j = 0; j < 4; ++j) acc[i][j] = (f32x4)(0.0f);

  bf16x8 bf[4], afA[4], afB[4];

#define PH_A(T, VMN, DO_STG)                                              \
  {                                                                       \
    const char* sb_ = lds + ((T) & 3) * 32768;                            \
    _Pragma("unroll") for (int j = 0; j < 4; ++j) bf[j] =                 \
        *reinterpret_cast<const bf16x8*>(sb_ + bOff + j * 1024);          \
    _Pragma("unroll") for (int i = 0; i < 4; ++i) afA[i] =                \
        *reinterpret_cast<const bf16x8*>(sb_ + aOff + i * 1024);          \
    if (DO_STG) STAGE_A((T) + 3);                                         \
    VMCNT(VMN);                                                           \
    __builtin_amdgcn_s_barrier();                                         \
    LGKM(0);                                                              \
    SCHEDB();                                                             \
    __builtin_amdgcn_s_setprio(1);                                        \
    _Pragma("unroll") for (int i = 0; i < 4; ++i)                         \
        _Pragma("unroll") for (int j = 0; j < 4; ++j) acc[i][j] =         \
            __builtin_amdgcn_mfma_f32_16x16x32_bf16(afA[i], bf[j],        \
                                                    acc[i][j], 0, 0, 0);  \
    __builtin_amdgcn_s_setprio(0);                                        \
    __builtin_amdgcn_s_barrier();                                         \
  }

#define PH_B(T, VMN, DO_STG)                                                 \
  {                                                                          \
    const char* sb_ = lds + ((T) & 3) * 32768;                               \
    _Pragma("unroll") for (int i = 0; i < 4; ++i) afB[i] =                   \
        *reinterpret_cast<const bf16x8*>(sb_ + aOff + 4096 + i * 1024);      \
    if (DO_STG) STAGE_B((T) + 3);                                            \
    VMCNT(VMN);                                                              \
    __builtin_amdgcn_s_barrier();                                            \
    LGKM(0);                                                                 \
    SCHEDB();                                                                \
    __builtin_amdgcn_s_setprio(1);                                           \
    _Pragma("unroll") for (int i = 0; i < 4; ++i)                            \
        _Pragma("unroll") for (int j = 0; j < 4; ++j) acc[4 + i][j] =        \
            __builtin_amdgcn_mfma_f32_16x16x32_bf16(afB[i], bf[j],           \
                                                    acc[4 + i][j], 0, 0, 0); \
    __builtin_amdgcn_s_setprio(0);                                           \
    __builtin_amdgcn_s_barrier();                                            \
  }

  // Prologue: 3 K-tiles in flight; ensure tile 0 landed (12 -> 8).
  STAGE_A(0); STAGE_B(0);
  STAGE_A(1); STAGE_B(1);
  STAGE_A(2); STAGE_B(2);
  VMCNT(8);
  __builtin_amdgcn_s_barrier();

  for (int kt = 0; kt < 29; ++kt) {
    PH_A(kt, 8, true);
    PH_B(kt, 8, true);
  }
  // Tail: stages ended at kt=28 (tile 31). Outstanding: t30(4)+t31(4).
  PH_A(29, 8, false);
  PH_B(29, 4, false);  // retire t30 before its first read
  PH_A(30, 4, false);
  PH_B(30, 0, false);  // retire t31
  // Final K-tile: no sync needed beyond lgkm for own reads.
  {
    const char* sb_ = lds + (31 & 3) * 32768;
#pragma unroll
    for (int j = 0; j < 4; ++j)
      bf[j] = *reinterpret_cast<const bf16x8*>(sb_ + bOff + j * 1024);
#pragma unroll
    for (int i = 0; i < 4; ++i)
      afA[i] = *reinterpret_cast<const bf16x8*>(sb_ + aOff + i * 1024);
#pragma unroll
    for (int i = 0; i < 4; ++i)
      afB[i] = *reinterpret_cast<const bf16x8*>(sb_ + aOff + 4096 + i * 1024);
    LGKM(0);
    SCHEDB();
#pragma unroll
    for (int i = 0; i < 4; ++i)
#pragma unroll
      for (int j = 0; j < 4; ++j) {
        acc[i][j] = __builtin_amdgcn_mfma_f32_16x16x32_bf16(afA[i], bf[j],
                                                            acc[i][j], 0, 0, 0);
        acc[4 + i][j] = __builtin_amdgcn_mfma_f32_16x16x32_bf16(
            afB[i], bf[j], acc[4 + i][j], 0, 0, 0);
      }
  }

  // Epilogue. C/D layout: col = lane&15, row = (lane>>4)*4 + reg (m89).
  const int col0 = n_tile * 256 + wn * 64 + (lane & 15);
  const int row0 = m_tile * 256 + wm * 128 + ((lane >> 4) << 2);
#pragma unroll
  for (int j = 0; j < 4; ++j) {
    float bv = bias[col0 + j * 16];
#pragma unroll
    for (int m = 0; m < 8; ++m) {
#pragma unroll
      for (int r = 0; r < 4; ++r) {
        C[(size_t)(row0 + m * 16 + r) * N_DIM + col0 + j * 16] =
            acc[m][j][r] + bv;
      }
    }
  }
#undef STAGE_A
#undef STAGE_B
#undef PH_A
#undef PH_B
}

extern "C" void kernel_launch(void* const* d_in, const int* in_sizes, int n_in,
                              void* d_out, int out_size, void* d_ws,
                              size_t ws_size, hipStream_t stream) {
  const float* x = (const float*)d_in[0];     // 8*8192*1024 fp32
  const float* w = (const float*)d_in[1];     // 1024*1024 fp32
  const float* bias = (const float*)d_in[2];  // 1024 fp32
  float* out = (float*)d_out;                 // 65536*1024 fp32

  bf16_t* xd = (bf16_t*)d_ws;               // 128 MB
  bf16_t* wd = xd + (size_t)M_DIM * K_DIM;  // +2 MB

  // Blocks [0,512): w (1 item/thread). Blocks [512,4608): x (grid-stride).
  quant_dequant_kernel<<<4608, 256, 0, stream>>>(
      x, xd, (long long)M_DIM * K_DIM / 8, w, wd,
      (long long)K_DIM * N_DIM / 8);

  mx_gemm<<<(M_DIM / 256) * (N_DIM / 256), 512, 0, stream>>>(xd, wd, bias,
                                                             out);
}